// Round 4
// baseline (373.231 us; speedup 1.0000x reference)
//
#include <hip/hip_runtime.h>
#include <hip/hip_bf16.h>
#include <cstdint>
#include <cstddef>

#define D_ 1024
#define H_ 4096
#define E_ 16
#define B_ 2048

constexpr int CAP = 384;   // per-expert slot capacity (mean 256, ~8 sigma)

typedef __attribute__((ext_vector_type(4))) float f32x4;
typedef __attribute__((ext_vector_type(8))) short bf16x8;

__device__ __forceinline__ unsigned pack2(float a, float b) {
  __hip_bfloat162 h = __float22bfloat162_rn(make_float2(a, b));
  union { __hip_bfloat162 h2; unsigned u; } cv; cv.h2 = h;
  return cv.u;   // a in low 16, b in high 16, RNE (v_cvt_pk_bf16_f32)
}
__device__ __forceinline__ float bflo(unsigned u) { return __uint_as_float(u << 16); }
__device__ __forceinline__ float bfhi(unsigned u) { return __uint_as_float(u & 0xffff0000u); }

#define GLL16(g, l)                                                         \
  __builtin_amdgcn_global_load_lds(                                         \
      (const __attribute__((address_space(1))) void*)(g),                   \
      (__attribute__((address_space(3))) void*)(l), 16, 0, 0)

#define WAITV(n) asm volatile("s_waitcnt vmcnt(" #n ")" ::: "memory")
#define BAR() __builtin_amdgcn_s_barrier()

// ================= gating: LN(x)@norm(keys) -> top2 -> rmeta + bf16 X gather =================
__global__ __launch_bounds__(256) void moe_gating3(
    const float* __restrict__ x, const float* __restrict__ gamma,
    const float* __restrict__ beta, const float* __restrict__ keys,
    int* __restrict__ cnt, int4* __restrict__ rmi, float2* __restrict__ rmg,
    unsigned short* __restrict__ xg)
{
  const int b = blockIdx.x, t = threadIdx.x;
  const int w = t >> 6;
  const float4 xv = ((const float4*)(x + (size_t)b * D_))[t];  // d = 4t..4t+3
  float s  = xv.x + xv.y + xv.z + xv.w;
  float sq = xv.x*xv.x + xv.y*xv.y + xv.z*xv.z + xv.w*xv.w;
#pragma unroll
  for (int off = 32; off >= 1; off >>= 1) {
    s  += __shfl_down(s, off);
    sq += __shfl_down(sq, off);
  }
  __shared__ float ssum[4], ssq[4], sstat[2];
  if ((t & 63) == 0) { ssum[w] = s; ssq[w] = sq; }
  __syncthreads();
  if (t == 0) {
    float S = ssum[0] + ssum[1] + ssum[2] + ssum[3];
    float Q = ssq[0] + ssq[1] + ssq[2] + ssq[3];
    float mu  = S * (1.0f / D_);
    float var = Q * (1.0f / D_) - mu * mu;
    sstat[0] = mu; sstat[1] = rsqrtf(var + 1e-5f);
  }
  __syncthreads();
  const float mu = sstat[0], rstd = sstat[1];
  const float4 gv = ((const float4*)gamma)[t];
  const float4 bv = ((const float4*)beta)[t];
  float xn[4] = {(xv.x-mu)*rstd*gv.x+bv.x, (xv.y-mu)*rstd*gv.y+bv.y,
                 (xv.z-mu)*rstd*gv.z+bv.z, (xv.w-mu)*rstd*gv.w+bv.w};
  float acc[E_];
#pragma unroll
  for (int e2 = 0; e2 < E_; ++e2) acc[e2] = 0.f;
#pragma unroll
  for (int j = 0; j < 4; ++j) {
    const int d = 4*t + j;
    const float* kr = keys + (size_t)d * E_;
    float kv[E_];
#pragma unroll
    for (int e2 = 0; e2 < E_; ++e2) kv[e2] = kr[e2];
    float nq = 0.f;
#pragma unroll
    for (int e2 = 0; e2 < E_; ++e2) nq += kv[e2] * kv[e2];
    const float sc = xn[j] / fmaxf(sqrtf(nq), 1e-12f);
#pragma unroll
    for (int e2 = 0; e2 < E_; ++e2) acc[e2] += sc * kv[e2];
  }
  // wave butterfly reduce (all 16 logits), then 4-wave combine
#pragma unroll
  for (int off = 1; off < 64; off <<= 1) {
#pragma unroll
    for (int e2 = 0; e2 < E_; ++e2) acc[e2] += __shfl_xor(acc[e2], off);
  }
  __shared__ float wred[4][E_];
  if ((t & 63) == 0) {
#pragma unroll
    for (int e2 = 0; e2 < E_; ++e2) wred[w][e2] = acc[e2];
  }
  __syncthreads();
  __shared__ int sE[2], sP[2];
  if (t == 0) {
    float lg[E_];
#pragma unroll
    for (int e2 = 0; e2 < E_; ++e2)
      lg[e2] = wred[0][e2] + wred[1][e2] + wred[2][e2] + wred[3][e2];
    float v0 = -1e30f; int e0 = 0;
    for (int e2 = 0; e2 < E_; ++e2) { if (lg[e2] > v0) { v0 = lg[e2]; e0 = e2; } }
    float v1 = -1e30f; int e1 = 0;
    for (int e2 = 0; e2 < E_; ++e2) { if (e2 == e0) continue; if (lg[e2] > v1) { v1 = lg[e2]; e1 = e2; } }
    const float g0 = 1.f / (1.f + __expf(v1 - v0));
    const float g1 = 1.f - g0;
    int p0 = atomicAdd(cnt + e0, 1); if (p0 >= CAP) p0 = CAP - 1;
    int p1 = atomicAdd(cnt + e1, 1); if (p1 >= CAP) p1 = CAP - 1;
    rmi[b] = make_int4(e0, p0, e1, p1);
    rmg[b] = make_float2(g0, g1);
    sE[0] = e0; sP[0] = p0;
    sE[1] = e1; sP[1] = p1;
  }
  __syncthreads();
  const uint2 pk = make_uint2(pack2(xv.x, xv.y), pack2(xv.z, xv.w));
#pragma unroll
  for (int i = 0; i < 2; ++i)
    ((uint2*)(xg + ((size_t)sE[i] * CAP + sP[i]) * D_))[t] = pk;
}

// ================= grouped GEMM: dst = [relu](A @ W [+ bias]) -> bf16 =================
// Block: 512 thr, tile M=384 x N=64, Kstep=32. Streams its W panel exactly once.
// A: bf16, rows of length KLEN, staged via global_load_lds with chunk-XOR swizzle
//    (pre-swizzled global source, swizzled read -> 2-way bank = free).
// B: fp32 W panel staged via global_load_lds into 1040B-padded groups (2-way banks).
// Wave grid 4 row-waves x 2 col-waves: A-LDS 48 KiB/phase, B-LDS 32 KiB/phase.
// NBUF=2 (g1: 64.25 KiB LDS, 2 blocks/CU) or NBUF=4 (g2: 128.5 KiB, 3-phase lookahead).
template<int KLEN, int WN, int NBUF, bool RELU>
__global__ void __launch_bounds__(512, (NBUF == 2) ? 4 : 2)
moe_gemm(const unsigned short* __restrict__ Asrc, const float* __restrict__ W,
         const float* __restrict__ bias, const int* __restrict__ cnt,
         unsigned short* __restrict__ dst)
{
  constexpr int NPHASE = KLEN / 32;
  constexpr int NT = WN / 64;                 // N-tiles per expert
  const int bx = blockIdx.x;
  const int slotn = bx >> 3;
  const int e  = ((bx & 7) << 1) | (slotn / NT);   // 2 experts per XCD
  const int nt = slotn % NT;
  const int nb = nt * 64;

  const int t = threadIdx.x, w = t >> 6, lane = t & 63;
  const int l15 = lane & 15, l4 = lane >> 4;
  const int wr = w >> 1, wc = w & 1;          // 4 row-waves x 2 col-waves

  __shared__ __align__(16) unsigned short As[NBUF][CAP * 32];  // 24 KiB each
  __shared__ __align__(16) float Bs[NBUF][2080];               // 8.125 KiB each

  const int cntE = cnt[e];
  asm volatile("s_waitcnt vmcnt(0) lgkmcnt(0)" ::: "memory");  // keep vmcnt ledger clean

  const unsigned short* Ae = Asrc + (size_t)e * CAP * KLEN;
  const float* We = W + (size_t)e * KLEN * WN + nb;

  // A staging: chunk c = i*512+t; row=c>>2; source chunk = (c&3) ^ ((row>>1)&3); LDS linear.
  const unsigned short* srcA0; const unsigned short* srcA1; const unsigned short* srcA2;
  {
    const int c0 = t,        r0 = c0 >> 2;
    const int c1 = t + 512,  r1 = c1 >> 2;
    const int c2 = t + 1024, r2 = c2 >> 2;
    srcA0 = Ae + (size_t)r0 * KLEN + ((c0 & 3) ^ ((r0 >> 1) & 3)) * 8;
    srcA1 = Ae + (size_t)r1 * KLEN + ((c1 & 3) ^ ((r1 >> 1) & 3)) * 8;
    srcA2 = Ae + (size_t)r2 * KLEN + ((c2 & 3) ^ ((r2 >> 1) & 3)) * 8;
  }
  // B staging: wave w loads k-rows 4w..4w+3 (256B each) into padded group w (1040 B).
  const float* srcB = We + (size_t)(w * 4 + l4) * WN + l15 * 4;

#define STAGE(p, BUF) do {                                                  \
    const int ko_ = (p) * 32;                                               \
    GLL16(srcA0 + ko_, &As[BUF][(0 * 512 + w * 64) * 8]);                   \
    GLL16(srcA1 + ko_, &As[BUF][(1 * 512 + w * 64) * 8]);                   \
    GLL16(srcA2 + ko_, &As[BUF][(2 * 512 + w * 64) * 8]);                   \
    GLL16(srcB + (size_t)ko_ * WN, &Bs[BUF][w * 260]);                      \
  } while (0)

  f32x4 acc[6][2];
#pragma unroll
  for (int rf = 0; rf < 6; ++rf) { acc[rf][0] = f32x4{0,0,0,0}; acc[rf][1] = f32x4{0,0,0,0}; }

  const int swA = (l15 >> 1) & 3;             // A-read chunk XOR (== (row>>1)&3)

#define COMP(BUF) do {                                                      \
    float bfv[2][8];                                                        \
    _Pragma("unroll")                                                       \
    for (int cf = 0; cf < 2; ++cf)                                          \
      _Pragma("unroll")                                                     \
      for (int j2 = 0; j2 < 8; ++j2)                                        \
        bfv[cf][j2] = Bs[BUF][(l4 * 2 + (j2 >> 2)) * 260 + (j2 & 3) * 64    \
                              + wc * 32 + cf * 16 + l15];                   \
    union { unsigned u[4]; bf16x8 v; } BB[2];                               \
    _Pragma("unroll")                                                       \
    for (int cf = 0; cf < 2; ++cf)                                          \
      _Pragma("unroll")                                                     \
      for (int i2 = 0; i2 < 4; ++i2)                                        \
        BB[cf].u[i2] = pack2(bfv[cf][2*i2], bfv[cf][2*i2+1]);               \
    _Pragma("unroll")                                                       \
    for (int rf = 0; rf < 6; ++rf) {                                        \
      if (wr * 96 + rf * 16 < cntE) {                                       \
        const int row = wr * 96 + rf * 16 + l15;                            \
        const bf16x8 a = *(const bf16x8*)&As[BUF][(row * 4 + (l4 ^ swA)) * 8]; \
        acc[rf][0] = __builtin_amdgcn_mfma_f32_16x16x32_bf16(a, BB[0].v, acc[rf][0], 0,0,0); \
        acc[rf][1] = __builtin_amdgcn_mfma_f32_16x16x32_bf16(a, BB[1].v, acc[rf][1], 0,0,0); \
      }                                                                     \
    }                                                                       \
  } while (0)

  if constexpr (NBUF == 2) {
    STAGE(0, 0);
#pragma unroll 1
    for (int base = 0; base < NPHASE; base += 2) {
      if (base + 1 < NPHASE) { STAGE(base + 1, 1); WAITV(4); } else WAITV(0);
      BAR(); COMP(0); BAR();
      if (base + 2 < NPHASE) { STAGE(base + 2, 0); WAITV(4); } else WAITV(0);
      BAR(); COMP(1); BAR();
    }
  } else {
    STAGE(0, 0); STAGE(1, 1); STAGE(2, 2);
#pragma unroll 1
    for (int base = 0; base < NPHASE; base += 4) {
      if (base + 3 < NPHASE) { STAGE(base + 3, 3); WAITV(12); }
      else WAITV(8);
      BAR(); COMP(0); BAR();
      if (base + 4 < NPHASE) { STAGE(base + 4, 0); WAITV(12); }
      else WAITV(4);
      BAR(); COMP(1); BAR();
      if (base + 5 < NPHASE) { STAGE(base + 5, 1); WAITV(12); }
      else WAITV(0);
      BAR(); COMP(2); BAR();
      if (base + 6 < NPHASE) { STAGE(base + 6, 2); WAITV(12); }
      else WAITV(0);
      BAR(); COMP(3); BAR();
    }
  }
#undef STAGE
#undef COMP

  // epilogue: [relu(acc+bias)] -> dst bf16, 4-col packs via shfl
  unsigned short* dbase = dst + (size_t)e * CAP * WN + nb + wc * 32;
#pragma unroll
  for (int rf = 0; rf < 6; ++rf) {
#pragma unroll
    for (int cf = 0; cf < 2; ++cf) {
      float bv = 0.f;
      if constexpr (RELU) bv = bias[e * WN + nb + wc * 32 + cf * 16 + l15];
#pragma unroll
      for (int r = 0; r < 4; ++r) {
        const int row = wr * 96 + rf * 16 + l4 * 4 + r;
        float v = acc[rf][cf][r];
        if constexpr (RELU) v = fmaxf(v + bv, 0.f);
        const unsigned u01 = pack2(v, __shfl_xor(v, 1));
        const float uo = __shfl_xor(__uint_as_float(u01), 2);
        if ((l15 & 3) == 0)
          *(uint2*)(dbase + (size_t)row * WN + cf * 16 + l15) =
              make_uint2(u01, __float_as_uint(uo));
      }
    }
  }
}

// ================= combine: out[b] = g0*(eo0+b2[e0]) + g1*(eo1+b2[e1]) =================
__global__ __launch_bounds__(256) void moe_comb(
    const unsigned short* __restrict__ eo, const float* __restrict__ b2,
    const int4* __restrict__ rmi, const float2* __restrict__ rmg,
    float* __restrict__ out)
{
  const int b = blockIdx.x, t = threadIdx.x;
  const int4 m = rmi[b];
  const float2 g = rmg[b];
  const int c = t * 4;
  const uint2 ua = *(const uint2*)(eo + ((size_t)m.x * CAP + m.y) * D_ + c);
  const uint2 ub = *(const uint2*)(eo + ((size_t)m.z * CAP + m.w) * D_ + c);
  const float4 b2a = *(const float4*)(b2 + (size_t)m.x * D_ + c);
  const float4 b2b = *(const float4*)(b2 + (size_t)m.z * D_ + c);
  float4 o;
  o.x = g.x * (bflo(ua.x) + b2a.x) + g.y * (bflo(ub.x) + b2b.x);
  o.y = g.x * (bfhi(ua.x) + b2a.y) + g.y * (bfhi(ub.x) + b2b.y);
  o.z = g.x * (bflo(ua.y) + b2a.z) + g.y * (bflo(ub.y) + b2b.z);
  o.w = g.x * (bfhi(ua.y) + b2a.w) + g.y * (bfhi(ub.y) + b2b.w);
  *(float4*)(out + (size_t)b * D_ + c) = o;
}

// ======================= launch =======================
extern "C" void kernel_launch(void* const* d_in, const int* in_sizes, int n_in,
                              void* d_out, int out_size, void* d_ws, size_t ws_size,
                              hipStream_t stream) {
  const float* x     = (const float*)d_in[0];
  const float* gamma = (const float*)d_in[1];
  const float* beta  = (const float*)d_in[2];
  const float* keys  = (const float*)d_in[3];
  const float* W1    = (const float*)d_in[4];
  const float* b1    = (const float*)d_in[5];
  const float* W2    = (const float*)d_in[6];
  const float* b2    = (const float*)d_in[7];
  float* out = (float*)d_out;

  char* ws = (char*)d_ws;
  const size_t OFF_RMI = 256;
  const size_t OFF_RMG = OFF_RMI + (size_t)B_ * 16;
  const size_t OFF_XG  = OFF_RMG + (size_t)B_ * 8;
  const size_t XG_SZ   = (size_t)E_ * CAP * D_ * 2;            // 12 MiB (eo overlays)
  const size_t OFF_HW  = OFF_XG + XG_SZ;

  int*    cnt = (int*)ws;
  int4*   rmi = (int4*)(ws + OFF_RMI);
  float2* rmg = (float2*)(ws + OFF_RMG);
  unsigned short* xg  = (unsigned short*)(ws + OFF_XG);
  unsigned short* eo  = xg;                                    // xg dead after GEMM1
  unsigned short* hws = (unsigned short*)(ws + OFF_HW);        // 48 MiB

  (void)hipMemsetAsync(cnt, 0, E_ * sizeof(int), stream);

  moe_gating3<<<B_, 256, 0, stream>>>(x, gamma, beta, keys, cnt, rmi, rmg, xg);
  moe_gemm<D_, H_, 2, true ><<<E_ * (H_ / 64), 512, 0, stream>>>(xg,  W1, b1, cnt, hws);
  moe_gemm<H_, D_, 4, false><<<E_ * (D_ / 64), 512, 0, stream>>>(hws, W2, nullptr, cnt, eo);
  moe_comb<<<B_, 256, 0, stream>>>(eo, b2, rmi, rmg, out);
}

// Round 5
// 355.065 us; speedup vs baseline: 1.0512x; 1.0512x over previous
//
#include <hip/hip_runtime.h>
#include <hip/hip_bf16.h>
#include <cstdint>
#include <cstddef>

#define D_ 1024
#define H_ 4096
#define E_ 16
#define B_ 2048

constexpr int CAP = 384;   // per-expert slot capacity (mean 256, ~8 sigma)

typedef __attribute__((ext_vector_type(4))) float f32x4;
typedef __attribute__((ext_vector_type(8))) short bf16x8;

__device__ __forceinline__ unsigned pack2(float a, float b) {
  __hip_bfloat162 h = __float22bfloat162_rn(make_float2(a, b));
  union { __hip_bfloat162 h2; unsigned u; } cv; cv.h2 = h;
  return cv.u;   // a lo16, b hi16 (v_cvt_pk_bf16_f32, RNE)
}
__device__ __forceinline__ float bflo(unsigned u) { return __uint_as_float(u << 16); }
__device__ __forceinline__ float bfhi(unsigned u) { return __uint_as_float(u & 0xffff0000u); }

#define GLL16(g, l)                                                         \
  __builtin_amdgcn_global_load_lds(                                         \
      (const __attribute__((address_space(1))) void*)(g),                   \
      (__attribute__((address_space(3))) void*)(l), 16, 0, 0)

#define WAITV(n) asm volatile("s_waitcnt vmcnt(" #n ")" ::: "memory")
#define BAR() __builtin_amdgcn_s_barrier()

// ================= gating: LN(x)@norm(keys) -> top2 -> rmeta + bf16 X gather =================
__global__ __launch_bounds__(256) void moe_gating3(
    const float* __restrict__ x, const float* __restrict__ gamma,
    const float* __restrict__ beta, const float* __restrict__ keys,
    int* __restrict__ cnt, int4* __restrict__ rmi, float2* __restrict__ rmg,
    unsigned short* __restrict__ xg)
{
  const int b = blockIdx.x, t = threadIdx.x;
  const int w = t >> 6;
  const float4 xv = ((const float4*)(x + (size_t)b * D_))[t];  // d = 4t..4t+3
  float s  = xv.x + xv.y + xv.z + xv.w;
  float sq = xv.x*xv.x + xv.y*xv.y + xv.z*xv.z + xv.w*xv.w;
#pragma unroll
  for (int off = 32; off >= 1; off >>= 1) {
    s  += __shfl_down(s, off);
    sq += __shfl_down(sq, off);
  }
  __shared__ float ssum[4], ssq[4], sstat[2];
  if ((t & 63) == 0) { ssum[w] = s; ssq[w] = sq; }
  __syncthreads();
  if (t == 0) {
    float S = ssum[0] + ssum[1] + ssum[2] + ssum[3];
    float Q = ssq[0] + ssq[1] + ssq[2] + ssq[3];
    float mu  = S * (1.0f / D_);
    float var = Q * (1.0f / D_) - mu * mu;
    sstat[0] = mu; sstat[1] = rsqrtf(var + 1e-5f);
  }
  __syncthreads();
  const float mu = sstat[0], rstd = sstat[1];
  const float4 gv = ((const float4*)gamma)[t];
  const float4 bv = ((const float4*)beta)[t];
  float xn[4] = {(xv.x-mu)*rstd*gv.x+bv.x, (xv.y-mu)*rstd*gv.y+bv.y,
                 (xv.z-mu)*rstd*gv.z+bv.z, (xv.w-mu)*rstd*gv.w+bv.w};
  float acc[E_];
#pragma unroll
  for (int e2 = 0; e2 < E_; ++e2) acc[e2] = 0.f;
#pragma unroll
  for (int j = 0; j < 4; ++j) {
    const int d = 4*t + j;
    const float* kr = keys + (size_t)d * E_;
    float kv[E_];
#pragma unroll
    for (int e2 = 0; e2 < E_; ++e2) kv[e2] = kr[e2];
    float nq = 0.f;
#pragma unroll
    for (int e2 = 0; e2 < E_; ++e2) nq += kv[e2] * kv[e2];
    const float sc = xn[j] / fmaxf(sqrtf(nq), 1e-12f);
#pragma unroll
    for (int e2 = 0; e2 < E_; ++e2) acc[e2] += sc * kv[e2];
  }
#pragma unroll
  for (int off = 1; off < 64; off <<= 1) {
#pragma unroll
    for (int e2 = 0; e2 < E_; ++e2) acc[e2] += __shfl_xor(acc[e2], off);
  }
  __shared__ float wred[4][E_];
  if ((t & 63) == 0) {
#pragma unroll
    for (int e2 = 0; e2 < E_; ++e2) wred[w][e2] = acc[e2];
  }
  __syncthreads();
  __shared__ int sE[2], sP[2];
  if (t == 0) {
    float lg[E_];
#pragma unroll
    for (int e2 = 0; e2 < E_; ++e2)
      lg[e2] = wred[0][e2] + wred[1][e2] + wred[2][e2] + wred[3][e2];
    float v0 = -1e30f; int e0 = 0;
    for (int e2 = 0; e2 < E_; ++e2) { if (lg[e2] > v0) { v0 = lg[e2]; e0 = e2; } }
    float v1 = -1e30f; int e1 = 0;
    for (int e2 = 0; e2 < E_; ++e2) { if (e2 == e0) continue; if (lg[e2] > v1) { v1 = lg[e2]; e1 = e2; } }
    const float g0 = 1.f / (1.f + __expf(v1 - v0));
    const float g1 = 1.f - g0;
    int p0 = atomicAdd(cnt + e0, 1); if (p0 >= CAP) p0 = CAP - 1;
    int p1 = atomicAdd(cnt + e1, 1); if (p1 >= CAP) p1 = CAP - 1;
    rmi[b] = make_int4(e0, p0, e1, p1);
    rmg[b] = make_float2(g0, g1);
    sE[0] = e0; sP[0] = p0;
    sE[1] = e1; sP[1] = p1;
  }
  __syncthreads();
  const uint2 pk = make_uint2(pack2(xv.x, xv.y), pack2(xv.z, xv.w));
#pragma unroll
  for (int i = 0; i < 2; ++i)
    ((uint2*)(xg + ((size_t)sE[i] * CAP + sP[i]) * D_))[t] = pk;
}

// ================= grouped GEMM: dst = [relu](A @ W [+ bias]) -> bf16 =================
// M=384, N-tile=NTILE (64 or 32), Kstep=32, NBUF=2, 8 waves as 4row x 2col.
// A bf16 via global_load_lds (XOR-swizzled source, swizzled read -> conflict-free).
// B fp32 via global_load_lds into 1056B-padded groups (2-way banks = free).
// 2 blocks/CU resident (LDS <= 66 KiB); counted vmcnt; setprio around MFMA.
template<int KLEN, int WN, int NTILE, bool RELU>
__global__ void __launch_bounds__(512, 4)
moe_gemm(const unsigned short* __restrict__ Asrc, const float* __restrict__ W,
         const float* __restrict__ bias, const int* __restrict__ cnt,
         unsigned short* __restrict__ dst)
{
  constexpr int NPHASE = KLEN / 32;
  constexpr int NT  = WN / NTILE;             // N-tiles per expert
  constexpr int CF  = NTILE / 32;             // 16-col frags per col-wave
  constexpr int BW  = NTILE / 8;              // waves staging B (1 KiB each)
  constexpr int RPW = 32 / BW;                // k-rows per B-stage wave
  constexpr int LPR = 64 / RPW;               // lanes per k-row

  const int bx = blockIdx.x;
  const int slotn = bx >> 3;
  const int e  = ((bx & 7) << 1) | (slotn / NT);   // 2 experts per XCD
  const int nt = slotn % NT;
  const int nb = nt * NTILE;

  const int t = threadIdx.x, w = t >> 6, lane = t & 63;
  const int l15 = lane & 15, l4 = lane >> 4;
  const int wr = w >> 1, wc = w & 1;          // 4 row-waves x 2 col-waves

  __shared__ __align__(16) unsigned short As[2][CAP * 32];   // 24 KiB each
  __shared__ __align__(16) float Bs[2][BW * 264];            // 1056B-padded groups

  const int cntE = cnt[e];
  asm volatile("s_waitcnt vmcnt(0) lgkmcnt(0)" ::: "memory");

  const unsigned short* Ae = Asrc + (size_t)e * CAP * KLEN;
  const float* We = W + (size_t)e * KLEN * WN + nb;

  // A staging: chunk c=i*512+t; row=c>>2; src chunk=(c&3)^((row>>1)&3); LDS linear.
  const unsigned short *srcA0, *srcA1, *srcA2;
  {
    const int c0 = t,        r0 = c0 >> 2;
    const int c1 = t + 512,  r1 = c1 >> 2;
    const int c2 = t + 1024, r2 = c2 >> 2;
    srcA0 = Ae + (size_t)r0 * KLEN + ((c0 & 3) ^ ((r0 >> 1) & 3)) * 8;
    srcA1 = Ae + (size_t)r1 * KLEN + ((c1 & 3) ^ ((r1 >> 1) & 3)) * 8;
    srcA2 = Ae + (size_t)r2 * KLEN + ((c2 & 3) ^ ((r2 >> 1) & 3)) * 8;
  }
  const float* srcB = We + (size_t)(w * RPW + lane / LPR) * WN + (lane % LPR) * 4;

#define STAGE(p, BUF) do {                                                  \
    const int ko_ = (p) * 32;                                               \
    GLL16(srcA0 + ko_, &As[BUF][(0 * 512 + w * 64) * 8]);                   \
    GLL16(srcA1 + ko_, &As[BUF][(1 * 512 + w * 64) * 8]);                   \
    GLL16(srcA2 + ko_, &As[BUF][(2 * 512 + w * 64) * 8]);                   \
    if (BW == 8 || w < BW) GLL16(srcB + (size_t)ko_ * WN, &Bs[BUF][w * 264]); \
  } while (0)

#define WAIT_STAGE() do {                                                   \
    if (BW == 8) { WAITV(4); }                                              \
    else { if (w < BW) { WAITV(4); } else { WAITV(3); } }                   \
  } while (0)

  f32x4 acc[6][CF];
#pragma unroll
  for (int rf = 0; rf < 6; ++rf)
#pragma unroll
    for (int cf = 0; cf < CF; ++cf) acc[rf][cf] = f32x4{0,0,0,0};

  const int swA = (l15 >> 1) & 3;             // A-read chunk XOR

#define COMP(BUF) do {                                                      \
    float bfv[CF][8];                                                       \
    _Pragma("unroll")                                                       \
    for (int cf = 0; cf < CF; ++cf)                                         \
      _Pragma("unroll")                                                     \
      for (int j2 = 0; j2 < 8; ++j2) {                                      \
        const int k_ = l4 * 8 + j2;                                         \
        bfv[cf][j2] = Bs[BUF][(k_ / RPW) * 264 + (k_ % RPW) * NTILE         \
                              + wc * (NTILE / 2) + cf * 16 + l15];          \
      }                                                                     \
    union { unsigned u[4]; bf16x8 v; } BB[CF];                              \
    _Pragma("unroll")                                                       \
    for (int cf = 0; cf < CF; ++cf)                                         \
      _Pragma("unroll")                                                     \
      for (int i2 = 0; i2 < 4; ++i2)                                        \
        BB[cf].u[i2] = pack2(bfv[cf][2*i2], bfv[cf][2*i2+1]);               \
    __builtin_amdgcn_s_setprio(1);                                          \
    _Pragma("unroll")                                                       \
    for (int rf = 0; rf < 6; ++rf) {                                        \
      if (wr * 96 + rf * 16 < cntE) {                                       \
        const int row = wr * 96 + rf * 16 + l15;                            \
        const bf16x8 a = *(const bf16x8*)&As[BUF][(row * 4 + (l4 ^ swA)) * 8]; \
        _Pragma("unroll")                                                   \
        for (int cf = 0; cf < CF; ++cf)                                     \
          acc[rf][cf] = __builtin_amdgcn_mfma_f32_16x16x32_bf16(a, BB[cf].v, acc[rf][cf], 0,0,0); \
      }                                                                     \
    }                                                                       \
    __builtin_amdgcn_s_setprio(0);                                          \
  } while (0)

  STAGE(0, 0);
#pragma unroll 1
  for (int p = 0; p < NPHASE; p += 2) {
    if (p + 1 < NPHASE) { STAGE(p + 1, 1); WAIT_STAGE(); } else { WAITV(0); }
    BAR(); COMP(0); BAR();
    if (p + 2 < NPHASE) { STAGE(p + 2, 0); WAIT_STAGE(); } else { WAITV(0); }
    BAR(); COMP(1); BAR();
  }
#undef STAGE
#undef WAIT_STAGE
#undef COMP

  // epilogue: [relu(acc+bias)] -> dst bf16, 4-col packs via shfl
  unsigned short* dbase = dst + (size_t)e * CAP * WN + nb + wc * (NTILE / 2);
#pragma unroll
  for (int rf = 0; rf < 6; ++rf) {
#pragma unroll
    for (int cf = 0; cf < CF; ++cf) {
      float bv = 0.f;
      if constexpr (RELU) bv = bias[e * WN + nb + wc * (NTILE / 2) + cf * 16 + l15];
#pragma unroll
      for (int r = 0; r < 4; ++r) {
        const int row = wr * 96 + rf * 16 + l4 * 4 + r;
        float v = acc[rf][cf][r];
        if constexpr (RELU) v = fmaxf(v + bv, 0.f);
        const unsigned u01 = pack2(v, __shfl_xor(v, 1));
        const float uo = __shfl_xor(__uint_as_float(u01), 2);
        if ((l15 & 3) == 0)
          *(uint2*)(dbase + (size_t)row * WN + cf * 16 + l15) =
              make_uint2(u01, __float_as_uint(uo));
      }
    }
  }
}

// ================= combine: out[b] = g0*(eo0+b2[e0]) + g1*(eo1+b2[e1]) =================
__global__ __launch_bounds__(256) void moe_comb(
    const unsigned short* __restrict__ eo, const float* __restrict__ b2,
    const int4* __restrict__ rmi, const float2* __restrict__ rmg,
    float* __restrict__ out)
{
  const int b = blockIdx.x, t = threadIdx.x;
  const int4 m = rmi[b];
  const float2 g = rmg[b];
  const int c = t * 4;
  const uint2 ua = *(const uint2*)(eo + ((size_t)m.x * CAP + m.y) * D_ + c);
  const uint2 ub = *(const uint2*)(eo + ((size_t)m.z * CAP + m.w) * D_ + c);
  const float4 b2a = *(const float4*)(b2 + (size_t)m.x * D_ + c);
  const float4 b2b = *(const float4*)(b2 + (size_t)m.z * D_ + c);
  float4 o;
  o.x = g.x * (bflo(ua.x) + b2a.x) + g.y * (bflo(ub.x) + b2b.x);
  o.y = g.x * (bfhi(ua.x) + b2a.y) + g.y * (bfhi(ub.x) + b2b.y);
  o.z = g.x * (bflo(ua.y) + b2a.z) + g.y * (bflo(ub.y) + b2b.z);
  o.w = g.x * (bfhi(ua.y) + b2a.w) + g.y * (bfhi(ub.y) + b2b.w);
  *(float4*)(out + (size_t)b * D_ + c) = o;
}

// ======================= launch =======================
extern "C" void kernel_launch(void* const* d_in, const int* in_sizes, int n_in,
                              void* d_out, int out_size, void* d_ws, size_t ws_size,
                              hipStream_t stream) {
  const float* x     = (const float*)d_in[0];
  const float* gamma = (const float*)d_in[1];
  const float* beta  = (const float*)d_in[2];
  const float* keys  = (const float*)d_in[3];
  const float* W1    = (const float*)d_in[4];
  const float* b1    = (const float*)d_in[5];
  const float* W2    = (const float*)d_in[6];
  const float* b2    = (const float*)d_in[7];
  float* out = (float*)d_out;

  char* ws = (char*)d_ws;
  const size_t OFF_RMI = 256;
  const size_t OFF_RMG = OFF_RMI + (size_t)B_ * 16;
  const size_t OFF_XG  = OFF_RMG + (size_t)B_ * 8;
  const size_t XG_SZ   = (size_t)E_ * CAP * D_ * 2;            // 12 MiB (eo overlays)
  const size_t OFF_HW  = OFF_XG + XG_SZ;

  int*    cnt = (int*)ws;
  int4*   rmi = (int4*)(ws + OFF_RMI);
  float2* rmg = (float2*)(ws + OFF_RMG);
  unsigned short* xg  = (unsigned short*)(ws + OFF_XG);
  unsigned short* eo  = xg;                                    // xg dead after GEMM1
  unsigned short* hws = (unsigned short*)(ws + OFF_HW);        // 48 MiB

  (void)hipMemsetAsync(cnt, 0, E_ * sizeof(int), stream);

  moe_gating3<<<B_, 256, 0, stream>>>(x, gamma, beta, keys, cnt, rmi, rmg, xg);
  moe_gemm<D_, H_, 64, true ><<<E_ * (H_ / 64), 512, 0, stream>>>(xg,  W1, b1, cnt, hws);
  moe_gemm<H_, D_, 32, false><<<E_ * (D_ / 32), 512, 0, stream>>>(hws, W2, nullptr, cnt, eo);
  moe_comb<<<B_, 256, 0, stream>>>(eo, b2, rmi, rmg, out);
}